// Round 17
// baseline (235.431 us; speedup 1.0000x reference)
//
#include <hip/hip_runtime.h>
#include <cstdint>
#include <cstddef>

// ---------------- problem constants ----------------
static constexpr int NB  = 8;     // batch
static constexpr int S   = 512;   // seq len
static constexpr int HID = 1024;
static constexpr int NH  = 16;    // heads
static constexpr int DH  = 64;    // head dim
static constexpr int P2  = 1024;  // 2*ATT_SPAN

static constexpr float INV_S1 = 0.14433756729740643f;  // 1/sqrt(3*H)

typedef __bf16 v8bf  __attribute__((ext_vector_type(8)));
typedef __bf16 v4bf  __attribute__((ext_vector_type(4)));
typedef float  f32x4 __attribute__((ext_vector_type(4)));

#define MFMA16(acc, a, b) acc = __builtin_amdgcn_mfma_f32_16x16x32_bf16(a, b, acc, 0, 0, 0)

// direct global->LDS DMA, 16B per lane; LDS dest = uniform base + lane*16
#define GLOAD_LDS16(gp, lp) __builtin_amdgcn_global_load_lds( \
    (const __attribute__((address_space(1))) void*)(gp), \
    (__attribute__((address_space(3))) void*)(lp), 16, 0, 0)

// ---------------- fused cast fp32 -> bf16 over all 6 inputs ----------------
__global__ void castall(const float* __restrict__ x,  const float* __restrict__ wq,
                        const float* __restrict__ wk, const float* __restrict__ wv,
                        const float* __restrict__ wpk, const float* __restrict__ rel,
                        __bf16* __restrict__ ob) {
  size_t e = ((size_t)blockIdx.x * 256 + threadIdx.x) * 4;
  if (e >= 9437184) return;
  const float* src; size_t off;
  if (e < 4194304) { src = x; off = e; }
  else {
    int r = (int)((e - 4194304) >> 20);
    off = (e - 4194304) & 1048575;
    src = (r == 0) ? wq : (r == 1) ? wk : (r == 2) ? wv : (r == 3) ? wpk : rel;
  }
  float4 v = *(const float4*)(src + off);
  v4bf o;
  o[0] = (__bf16)v.x; o[1] = (__bf16)v.y; o[2] = (__bf16)v.z; o[3] = (__bf16)v.w;
  *(v4bf*)(ob + e) = o;
}

// ---------------- projection GEMM, bf16, BK=64, global_load_lds staging ------
// r15: flat 1-D grid of 832 working blocks. r16: XCD-aware remap (neutral but
// harmless; kept). NEW (r17): __launch_bounds__(256, 2). The (256,4) bound is
// the exact config that silently pinned attn's allocator at 64 VGPR and spilled
// ~13 MB/dispatch (r7 vs r10: fixing it was -13 us). proj's live state is
// LARGER (64 f32 acc + 8 v8bf frags + addressing; the unbounded m97-structure
// kernel allocates 164 VGPR + 64 AGPR) -> (256,4) likely forces scratch spill
// every K-step, invisible because proj never surfaces in top-5 counters.
// LDS (33 KB) caps residency at 4 blocks/CU regardless; if regs rise past 128
// residency drops to ~2 blocks/CU - m132's bound for that case (508 TF) is
// still ~1.8x our current ~280 TF, so downside is bounded.
__launch_bounds__(256, 2)
__global__ void proj_gemm(const __bf16* __restrict__ Xb, const __bf16* __restrict__ Rb,
                          const __bf16* __restrict__ Wqb, const __bf16* __restrict__ Wkb,
                          const __bf16* __restrict__ Wvb, const __bf16* __restrict__ Wpkb,
                          const float* __restrict__ bq, const float* __restrict__ bk_,
                          const float* __restrict__ bv_, const float* __restrict__ bpk,
                          __bf16* __restrict__ qo, __bf16* __restrict__ ko,
                          __bf16* __restrict__ vto, __bf16* __restrict__ po) {
  // decode: g = i*8 + x; x = XCD residue, i = slot within XCD (104 slots).
  const int g = blockIdx.x;
  const int x8 = g & 7, i = g >> 3;
  const int i13 = i / 13, r13 = i % 13;
  int z, mblk, nblk;
  if (r13 == 12) { z = 3; mblk = x8; nblk = i13; }
  else {
    int idx = i13 * 12 + r13;                    // [0,96)
    int mgroup = idx / 24, within = idx % 24;
    z = within >> 3; nblk = within & 7;
    mblk = mgroup * 8 + x8;
  }
  const int m0 = mblk * 128;
  const int n0 = nblk * 128;

  const __bf16* A; const __bf16* W; const float* bias; __bf16* out; float osc;
  if      (z == 0) { A = Xb; W = Wqb;  bias = bq;  out = qo;  osc = INV_S1; }
  else if (z == 1) { A = Xb; W = Wkb;  bias = bk_; out = ko;  osc = 1.0f; }
  else if (z == 2) { A = Xb; W = Wvb;  bias = bv_; out = vto; osc = 1.0f; }
  else             { A = Rb; W = Wpkb; bias = bpk; out = po;  osc = INV_S1; }
  const int K = 1024;

  __shared__ __bf16 Al[128 * 64];  // unpadded; phys seg = seg ^ (row&7)
  __shared__ __bf16 Bl[128 * 64];

  const int t = threadIdx.x;
  const int w = t >> 6, lane = t & 63, q4 = lane >> 4, cc = lane & 15;
  const int wm = w >> 1, wn = w & 1;
  const int srow_in = lane >> 3;
  const int sseg    = ((lane & 7) ^ srow_in) * 8;

  f32x4 acc[4][4] = {};

  for (int k0 = 0; k0 < K; k0 += 64) {
    __syncthreads();
    #pragma unroll
    for (int ii = 0; ii < 4; ii++) {
      int rr = w * 32 + ii * 8;
      int gr = rr + srow_in;
      GLOAD_LDS16(&A[(size_t)(m0 + gr) * K + k0 + sseg], &Al[rr * 64]);
      GLOAD_LDS16(&W[(size_t)(n0 + gr) * K + k0 + sseg], &Bl[rr * 64]);
    }
    __syncthreads();
    #pragma unroll
    for (int kk = 0; kk < 2; kk++) {
      v8bf af[4], bfg[4];
      const int phys = ((4 * kk + q4) ^ (cc & 7)) * 8;
      #pragma unroll
      for (int mt = 0; mt < 4; mt++)
        af[mt] = *(const v8bf*)(&Al[(wm * 64 + mt * 16 + cc) * 64 + phys]);
      #pragma unroll
      for (int nt = 0; nt < 4; nt++)
        bfg[nt] = *(const v8bf*)(&Bl[(wn * 64 + nt * 16 + cc) * 64 + phys]);
      #pragma unroll
      for (int mt = 0; mt < 4; mt++)
        #pragma unroll
        for (int nt = 0; nt < 4; nt++)
          MFMA16(acc[mt][nt], af[mt], bfg[nt]);
    }
  }

  #pragma unroll
  for (int mt = 0; mt < 4; mt++) {
    #pragma unroll
    for (int nt = 0; nt < 4; nt++) {
      int n = n0 + wn * 64 + nt * 16 + cc;
      float bsv = bias[n];
      if (z == 2) {
        int m_base = m0 + wm * 64 + mt * 16 + q4 * 4;
        int bb = m_base >> 9, ss = m_base & 511, hh = n >> 6, dd = n & 63;
        v4bf st;
        st[0] = (__bf16)(acc[mt][nt][0] + bsv);
        st[1] = (__bf16)(acc[mt][nt][1] + bsv);
        st[2] = (__bf16)(acc[mt][nt][2] + bsv);
        st[3] = (__bf16)(acc[mt][nt][3] + bsv);
        *(v4bf*)(&out[(((size_t)bb * 16 + hh) * 64 + dd) * 512 + ss]) = st;
      } else {
        #pragma unroll
        for (int r = 0; r < 4; r++) {
          int m = m0 + wm * 64 + mt * 16 + q4 * 4 + r;
          float val = (acc[mt][nt][r] + bsv) * osc;
          size_t idx;
          if (z < 2)
            idx = ((size_t)(m >> 9) * 16 + (n >> 6)) * (512 * 64) + (size_t)(m & 511) * 64 + (n & 63);
          else
            idx = (size_t)(n >> 6) * (1024 * 64) + (size_t)m * 64 + (n & 63);
          out[idx] = (__bf16)val;
        }
      }
    }
  }
}

// ---------------- fused disentangled attention: K prefetch + XCD swizzle ----
// ROUND-12 CHAMPION, verbatim (102.3-103.6 us). grid (8,128) remapped:
// flat = x+8*y; r8 = flat&7; q = flat>>3; bh = (q>>3)*8 + r8; i0 = (q&7)*64 —
// all 8 i-blocks of a bh share one XCD residue; FETCH 79->13.5 MB (r12).
// __launch_bounds__(256,2) — proven spill-free point. Loop-carried K set +
// U4 pos pair prefetch, T13 defer-max, shfl psum reduce, direct fp32 out,
// zero barriers. Q,pos pre-scaled by 1/sqrt(48); G carries residual sqrt(3)/2.
__launch_bounds__(256, 2)
__global__ void attn(const __bf16* __restrict__ qb, const __bf16* __restrict__ kb,
                     const __bf16* __restrict__ vtb, const __bf16* __restrict__ posb,
                     const float* __restrict__ mask,
                     float* __restrict__ out) {
  const int flat = blockIdx.x + 8 * blockIdx.y;   // [0,1024)
  const int r8 = flat & 7, qd = flat >> 3;
  const int bh = ((qd >> 3) << 3) + r8;           // 8 i-blocks of bh share residue
  const int i0 = (qd & 7) * 64;
  const int b = bh >> 4, h = bh & 15;

  __shared__ __bf16 Sb[64 * 136];   // [a][slot]: G at jj*2, H at jj*2+1, probs at 0..63

  const int t = threadIdx.x, w = t >> 6, lane = t & 63, q4 = lane >> 4, cc = lane & 15;
  const int arow = w * 16;
  const size_t bho = (size_t)bh * (S * DH);
  const __bf16* qp  = qb  + bho;
  const __bf16* kp  = kb  + bho;
  const __bf16* vtp = vtb + bho;   // [d][s]
  const __bf16* pp  = posb + (size_t)h * (P2 * DH);

  v8bf aq0 = *(const v8bf*)(&qp[(size_t)(i0 + arow + cc) * DH + q4 * 8]);
  v8bf aq1 = *(const v8bf*)(&qp[(size_t)(i0 + arow + cc) * DH + 32 + q4 * 8]);

  f32x4 Oc[4] = {};
  float mrow[4], lrow[4];
  #pragma unroll
  for (int r = 0; r < 4; r++) { mrow[r] = -__builtin_inff(); lrow[r] = 0.f; }

#define LDPN(d0, d1, PW) { int p_ = (PW) + cc; p_ = min(max(p_, 0), P2 - 1); \
  const __bf16* pr_ = &pp[(size_t)p_ * DH + q4 * 8]; \
  d0 = *(const v8bf*)pr_; d1 = *(const v8bf*)(pr_ + 32); }
#define LDKJ(d0, d1, NT, J) { const __bf16* kr_ = &kp[(size_t)((J) + (NT) * 16 + cc) * DH + q4 * 8]; \
  d0 = *(const v8bf*)kr_; d1 = *(const v8bf*)(kr_ + 32); }
#define GT(U, P0, P1) { f32x4 g_ = {}; MFMA16(g_, aq0, P0); MFMA16(g_, aq1, P1); \
  _Pragma("unroll") for (int r_ = 0; r_ < 4; r_++) { \
    int jj_ = q4 * 4 + r_ - 16 * (U) - cc + 63; \
    if ((unsigned)jj_ < 64u) Sb[(arow + q4 * 4 + r_) * 136 + jj_ * 2] = (__bf16)(g_[r_] * 0.8660254f); } }
#define HT(U, NT, P0, P1, K0, K1) { f32x4 h_ = {}; MFMA16(h_, P0, K0); MFMA16(h_, P1, K1); \
  _Pragma("unroll") for (int r_ = 0; r_ < 4; r_++) { \
    int ar_ = 16 * (U) + q4 * 4 + r_ + 16 * (NT) + cc - 63; \
    if ((unsigned)ar_ < 16u) Sb[(arow + ar_) * 136 + (16 * (NT) + cc) * 2 + 1] = (__bf16)h_[r_]; } }
#define CT(NT, K0, K1) { f32x4 c_ = {}; MFMA16(c_, aq0, K0); MFMA16(c_, aq1, K1); accc[NT] = c_; }

  // loop-carried prefetch state: K tile (4 pairs) + pos U=4 pair for CURRENT jt
  v8bf k00,k01,k10,k11,k20,k21,k30,k31;
  v8bf pn0, pn1;
  LDKJ(k00,k01,0,0); LDKJ(k10,k11,1,0); LDKJ(k20,k21,2,0); LDKJ(k30,k31,3,0);
  LDPN(pn0, pn1, i0 + arow + 449 + 64);   // jt=0: pw0 + 64

  for (int jt = 0; jt < 8; jt++) {
    const int j0 = jt * 64;
    const int pw0 = i0 + arow - j0 + 449;
    const int jn = (j0 + 64 <= 448) ? (j0 + 64) : 448;   // next-tile base (clamped)

    float mk[4];
    #pragma unroll
    for (int nt = 0; nt < 4; nt++) mk[nt] = mask[(size_t)b * S + j0 + nt * 16 + cc];

    f32x4 accc[4];
    v8bf p30,p31,p20,p21,p10,p11,p00,p01;

    LDPN(p30, p31, pw0 + 48);
    GT(4, pn0, pn1); HT(4, 0, pn0, pn1, k00, k01); CT(0, k00, k01);
    LDPN(p20, p21, pw0 + 32);
    GT(3, p30, p31); HT(3, 0, p30, p31, k00, k01); HT(3, 1, p30, p31, k10, k11); CT(1, k10, k11);
    LDKJ(k00, k01, 0, jn);          // k00/k01 dead -> reload for next tile
    LDPN(p10, p11, pw0 + 16);
    GT(2, p20, p21); HT(2, 1, p20, p21, k10, k11); HT(2, 2, p20, p21, k20, k21); CT(2, k20, k21);
    LDKJ(k10, k11, 1, jn);
    LDPN(p00, p01, pw0);
    GT(1, p10, p11); HT(1, 2, p10, p11, k20, k21); HT(1, 3, p10, p11, k30, k31); CT(3, k30, k31);
    LDKJ(k20, k21, 2, jn);
    GT(0, p00, p01); HT(0, 3, p00, p01, k30, k31);
    LDKJ(k30, k31, 3, jn);
    LDPN(pn0, pn1, pw0);            // next jt's U=4 pair: next_pw0 + 64 == pw0

    float sc[4][4];
    #pragma unroll
    for (int nt = 0; nt < 4; nt++) {
      int jj = nt * 16 + cc;
      #pragma unroll
      for (int r = 0; r < 4; r++) {
        const __bf16* slot = &Sb[(arow + q4 * 4 + r) * 136 + jj * 2];
        sc[nt][r] = accc[nt][r] + (float)slot[0] + (float)slot[1] + mk[nt];
      }
    }

    // T13 defer-max: per-lane local max; full reduce + rescale only if needed
    float tl[4];
    #pragma unroll
    for (int r = 0; r < 4; r++)
      tl[r] = fmaxf(fmaxf(sc[0][r], sc[1][r]), fmaxf(sc[2][r], sc[3][r]));
    float dmax = tl[0] - mrow[0];
    #pragma unroll
    for (int r = 1; r < 4; r++) dmax = fmaxf(dmax, tl[r] - mrow[r]);

    if (__any(dmax > 8.0f)) {
      float tmax[4];
      #pragma unroll
      for (int r = 0; r < 4; r++) tmax[r] = tl[r];
      #pragma unroll
      for (int off = 1; off < 16; off <<= 1)
        #pragma unroll
        for (int r = 0; r < 4; r++) tmax[r] = fmaxf(tmax[r], __shfl_xor(tmax[r], off, 64));
      #pragma unroll
      for (int r = 0; r < 4; r++) {
        float mnew = fmaxf(mrow[r], tmax[r]);
        float alpha = __expf(mrow[r] - mnew);
        mrow[r] = mnew;
        lrow[r] *= alpha;
        #pragma unroll
        for (int dt = 0; dt < 4; dt++) Oc[dt][r] *= alpha;
      }
    }

    v8bf vf[2][4];
    #pragma unroll
    for (int kk = 0; kk < 2; kk++)
      #pragma unroll
      for (int dt = 0; dt < 4; dt++)
        vf[kk][dt] = *(const v8bf*)(&vtp[(size_t)(dt * 16 + cc) * S + j0 + kk * 32 + q4 * 8]);

    float psum[4] = { 0.f, 0.f, 0.f, 0.f };
    #pragma unroll
    for (int nt = 0; nt < 4; nt++)
      #pragma unroll
      for (int r = 0; r < 4; r++) {
        float p = __expf(sc[nt][r] - mrow[r]);
        psum[r] += p;
        Sb[(arow + q4 * 4 + r) * 136 + nt * 16 + cc] = (__bf16)p;
      }
    #pragma unroll
    for (int off = 1; off < 16; off <<= 1)
      #pragma unroll
      for (int r = 0; r < 4; r++) psum[r] += __shfl_xor(psum[r], off, 64);
    #pragma unroll
    for (int r = 0; r < 4; r++) lrow[r] += psum[r];

    #pragma unroll
    for (int kk = 0; kk < 2; kk++) {
      v8bf ap = *(const v8bf*)(&Sb[(arow + cc) * 136 + kk * 32 + q4 * 8]);
      #pragma unroll
      for (int dt = 0; dt < 4; dt++)
        MFMA16(Oc[dt], ap, vf[kk][dt]);
    }
  }

  // epilogue: normalize and store fp32 output directly
  #pragma unroll
  for (int r = 0; r < 4; r++) {
    int i = i0 + arow + q4 * 4 + r;
    float rl = 1.0f / lrow[r];
    float* orow = &out[((size_t)b * S + i) * HID + h * 64];
    #pragma unroll
    for (int dt = 0; dt < 4; dt++)
      orow[dt * 16 + cc] = Oc[dt][r] * rl;
  }
#undef LDPN
#undef LDKJ
#undef GT
#undef HT
#undef CT
}

// ---------------- launch ----------------
extern "C" void kernel_launch(void* const* d_in, const int* in_sizes, int n_in,
                              void* d_out, int out_size, void* d_ws, size_t ws_size,
                              hipStream_t stream) {
  const float* hs   = (const float*)d_in[0];
  const float* mask = (const float*)d_in[1];
  const float* Wq  = (const float*)d_in[3];
  const float* bq  = (const float*)d_in[4];
  const float* Wk  = (const float*)d_in[5];
  const float* bk  = (const float*)d_in[6];
  const float* Wv  = (const float*)d_in[7];
  const float* bv  = (const float*)d_in[8];
  const float* Wpk = (const float*)d_in[9];
  const float* bpk = (const float*)d_in[10];
  const float* rel = (const float*)d_in[11];
  float* out = (float*)d_out;

  char* ws = (char*)d_ws;
  __bf16* cb   = (__bf16*)ws;                      // casts: X|Wq|Wk|Wv|Wpk|rel = 18 MB
  __bf16* Xb   = cb;
  __bf16* Wqb  = cb + 4194304;
  __bf16* Wkb  = cb + 5242880;
  __bf16* Wvb  = cb + 6291456;
  __bf16* Wpkb = cb + 7340032;
  __bf16* Rb   = cb + 8388608;
  __bf16* qb   = (__bf16*)(ws + 18874368);         // [b][h][s][d] 8 MB (pre-scaled)
  __bf16* kb   = (__bf16*)(ws + 27262976);         // [b][h][s][d] 8 MB
  __bf16* vtb  = (__bf16*)(ws + 35651584);         // [b][h][d][s] 8 MB
  __bf16* posb = (__bf16*)(ws + 44040192);         // [h][p][d]    2 MB (pre-scaled)

  castall<<<9216, 256, 0, stream>>>(hs, Wq, Wk, Wv, Wpk, rel, cb);

  proj_gemm<<<832, 256, 0, stream>>>(Xb, Rb, Wqb, Wkb, Wvb, Wpkb,
                                     bq, bk, bv, bpk, qb, kb, vtb, posb);

  attn<<<dim3(8, 128), 256, 0, stream>>>(qb, kb, vtb, posb, mask, out);
}

// Round 20
// 226.901 us; speedup vs baseline: 1.0376x; 1.0376x over previous
//
#include <hip/hip_runtime.h>
#include <cstdint>
#include <cstddef>

// ---------------- problem constants ----------------
static constexpr int NB  = 8;     // batch
static constexpr int S   = 512;   // seq len
static constexpr int HID = 1024;
static constexpr int NH  = 16;    // heads
static constexpr int DH  = 64;    // head dim
static constexpr int P2  = 1024;  // 2*ATT_SPAN

static constexpr float INV_S1 = 0.14433756729740643f;  // 1/sqrt(3*H)

typedef __bf16 v8bf  __attribute__((ext_vector_type(8)));
typedef __bf16 v4bf  __attribute__((ext_vector_type(4)));
typedef float  f32x4 __attribute__((ext_vector_type(4)));

#define MFMA16(acc, a, b) acc = __builtin_amdgcn_mfma_f32_16x16x32_bf16(a, b, acc, 0, 0, 0)

// direct global->LDS DMA, 16B per lane; LDS dest = uniform base + lane*16
#define GLOAD_LDS16(gp, lp) __builtin_amdgcn_global_load_lds( \
    (const __attribute__((address_space(1))) void*)(gp), \
    (__attribute__((address_space(3))) void*)(lp), 16, 0, 0)

// ---------------- fused cast fp32 -> bf16 over all 6 inputs ----------------
__global__ void castall(const float* __restrict__ x,  const float* __restrict__ wq,
                        const float* __restrict__ wk, const float* __restrict__ wv,
                        const float* __restrict__ wpk, const float* __restrict__ rel,
                        __bf16* __restrict__ ob) {
  size_t e = ((size_t)blockIdx.x * 256 + threadIdx.x) * 4;
  if (e >= 9437184) return;
  const float* src; size_t off;
  if (e < 4194304) { src = x; off = e; }
  else {
    int r = (int)((e - 4194304) >> 20);
    off = (e - 4194304) & 1048575;
    src = (r == 0) ? wq : (r == 1) ? wk : (r == 2) ? wv : (r == 3) ? wpk : rel;
  }
  float4 v = *(const float4*)(src + off);
  v4bf o;
  o[0] = (__bf16)v.x; o[1] = (__bf16)v.y; o[2] = (__bf16)v.z; o[3] = (__bf16)v.w;
  *(v4bf*)(ob + e) = o;
}

// ---------------- projection GEMM, bf16, BK=64, global_load_lds staging ------
// ROUND-12 CONFIG (measured best: 227.49 us total). (256,4) bounds: r17 proved
// (256,2) HALVES proj residency (4 -> 2 blocks/CU; the 2nd bounds arg acts as
// a residency cap, per r10/r12 attn data) and costs +8 us. The dim3(32,8,4)
// grid: r15's flat packing and r16's XCD remap were both neutral (proj is
// structure-bound at this tile shape, not tail- or fetch-bound).
__launch_bounds__(256, 4)
__global__ void proj_gemm(const __bf16* __restrict__ Xb, const __bf16* __restrict__ Rb,
                          const __bf16* __restrict__ Wqb, const __bf16* __restrict__ Wkb,
                          const __bf16* __restrict__ Wvb, const __bf16* __restrict__ Wpkb,
                          const float* __restrict__ bq, const float* __restrict__ bk_,
                          const float* __restrict__ bv_, const float* __restrict__ bpk,
                          __bf16* __restrict__ qo, __bf16* __restrict__ ko,
                          __bf16* __restrict__ vto, __bf16* __restrict__ po) {
  const int z = blockIdx.z;
  const __bf16* A; const __bf16* W; const float* bias; __bf16* out; int M; float osc;
  if      (z == 0) { A = Xb; W = Wqb;  bias = bq;  out = qo;  M = 4096; osc = INV_S1; }
  else if (z == 1) { A = Xb; W = Wkb;  bias = bk_; out = ko;  M = 4096; osc = 1.0f; }
  else if (z == 2) { A = Xb; W = Wvb;  bias = bv_; out = vto; M = 4096; osc = 1.0f; }
  else             { A = Rb; W = Wpkb; bias = bpk; out = po;  M = 1024; osc = INV_S1; }
  const int m0 = blockIdx.x * 128;
  if (m0 >= M) return;
  const int n0 = blockIdx.y * 128;
  const int K = 1024;

  __shared__ __bf16 Al[128 * 64];  // unpadded; phys seg = seg ^ (row&7)
  __shared__ __bf16 Bl[128 * 64];

  const int t = threadIdx.x;
  const int w = t >> 6, lane = t & 63, q4 = lane >> 4, cc = lane & 15;
  const int wm = w >> 1, wn = w & 1;
  const int srow_in = lane >> 3;
  const int sseg    = ((lane & 7) ^ srow_in) * 8;

  f32x4 acc[4][4] = {};

  for (int k0 = 0; k0 < K; k0 += 64) {
    __syncthreads();
    #pragma unroll
    for (int i = 0; i < 4; i++) {
      int rr = w * 32 + i * 8;
      int gr = rr + srow_in;
      GLOAD_LDS16(&A[(size_t)(m0 + gr) * K + k0 + sseg], &Al[rr * 64]);
      GLOAD_LDS16(&W[(size_t)(n0 + gr) * K + k0 + sseg], &Bl[rr * 64]);
    }
    __syncthreads();
    #pragma unroll
    for (int kk = 0; kk < 2; kk++) {
      v8bf af[4], bfg[4];
      const int phys = ((4 * kk + q4) ^ (cc & 7)) * 8;
      #pragma unroll
      for (int mt = 0; mt < 4; mt++)
        af[mt] = *(const v8bf*)(&Al[(wm * 64 + mt * 16 + cc) * 64 + phys]);
      #pragma unroll
      for (int nt = 0; nt < 4; nt++)
        bfg[nt] = *(const v8bf*)(&Bl[(wn * 64 + nt * 16 + cc) * 64 + phys]);
      #pragma unroll
      for (int mt = 0; mt < 4; mt++)
        #pragma unroll
        for (int nt = 0; nt < 4; nt++)
          MFMA16(acc[mt][nt], af[mt], bfg[nt]);
    }
  }

  #pragma unroll
  for (int mt = 0; mt < 4; mt++) {
    #pragma unroll
    for (int nt = 0; nt < 4; nt++) {
      int n = n0 + wn * 64 + nt * 16 + cc;
      float bsv = bias[n];
      if (z == 2) {
        int m_base = m0 + wm * 64 + mt * 16 + q4 * 4;
        int bb = m_base >> 9, ss = m_base & 511, hh = n >> 6, dd = n & 63;
        v4bf st;
        st[0] = (__bf16)(acc[mt][nt][0] + bsv);
        st[1] = (__bf16)(acc[mt][nt][1] + bsv);
        st[2] = (__bf16)(acc[mt][nt][2] + bsv);
        st[3] = (__bf16)(acc[mt][nt][3] + bsv);
        *(v4bf*)(&out[(((size_t)bb * 16 + hh) * 64 + dd) * 512 + ss]) = st;
      } else {
        #pragma unroll
        for (int r = 0; r < 4; r++) {
          int m = m0 + wm * 64 + mt * 16 + q4 * 4 + r;
          float val = (acc[mt][nt][r] + bsv) * osc;
          size_t idx;
          if (z < 2)
            idx = ((size_t)(m >> 9) * 16 + (n >> 6)) * (512 * 64) + (size_t)(m & 511) * 64 + (n & 63);
          else
            idx = (size_t)(n >> 6) * (1024 * 64) + (size_t)m * 64 + (n & 63);
          out[idx] = (__bf16)val;
        }
      }
    }
  }
}

// ---------------- fused disentangled attention: K prefetch + XCD swizzle ----
// ROUND-12 CHAMPION, verbatim (102.3-103.6 us). grid (8,128) remapped:
// flat = x+8*y; r8 = flat&7; q = flat>>3; bh = (q>>3)*8 + r8; i0 = (q&7)*64 —
// all 8 i-blocks of a bh share one XCD residue; FETCH 79->13.5 MB (r12).
// __launch_bounds__(256,2) — proven spill-free point. Loop-carried K set +
// U4 pos pair prefetch, T13 defer-max, shfl psum reduce, direct fp32 out,
// zero barriers. Q,pos pre-scaled by 1/sqrt(48); G carries residual sqrt(3)/2.
__launch_bounds__(256, 2)
__global__ void attn(const __bf16* __restrict__ qb, const __bf16* __restrict__ kb,
                     const __bf16* __restrict__ vtb, const __bf16* __restrict__ posb,
                     const float* __restrict__ mask,
                     float* __restrict__ out) {
  const int flat = blockIdx.x + 8 * blockIdx.y;   // [0,1024)
  const int r8 = flat & 7, qd = flat >> 3;
  const int bh = ((qd >> 3) << 3) + r8;           // 8 i-blocks of bh share residue
  const int i0 = (qd & 7) * 64;
  const int b = bh >> 4, h = bh & 15;

  __shared__ __bf16 Sb[64 * 136];   // [a][slot]: G at jj*2, H at jj*2+1, probs at 0..63

  const int t = threadIdx.x, w = t >> 6, lane = t & 63, q4 = lane >> 4, cc = lane & 15;
  const int arow = w * 16;
  const size_t bho = (size_t)bh * (S * DH);
  const __bf16* qp  = qb  + bho;
  const __bf16* kp  = kb  + bho;
  const __bf16* vtp = vtb + bho;   // [d][s]
  const __bf16* pp  = posb + (size_t)h * (P2 * DH);

  v8bf aq0 = *(const v8bf*)(&qp[(size_t)(i0 + arow + cc) * DH + q4 * 8]);
  v8bf aq1 = *(const v8bf*)(&qp[(size_t)(i0 + arow + cc) * DH + 32 + q4 * 8]);

  f32x4 Oc[4] = {};
  float mrow[4], lrow[4];
  #pragma unroll
  for (int r = 0; r < 4; r++) { mrow[r] = -__builtin_inff(); lrow[r] = 0.f; }

#define LDPN(d0, d1, PW) { int p_ = (PW) + cc; p_ = min(max(p_, 0), P2 - 1); \
  const __bf16* pr_ = &pp[(size_t)p_ * DH + q4 * 8]; \
  d0 = *(const v8bf*)pr_; d1 = *(const v8bf*)(pr_ + 32); }
#define LDKJ(d0, d1, NT, J) { const __bf16* kr_ = &kp[(size_t)((J) + (NT) * 16 + cc) * DH + q4 * 8]; \
  d0 = *(const v8bf*)kr_; d1 = *(const v8bf*)(kr_ + 32); }
#define GT(U, P0, P1) { f32x4 g_ = {}; MFMA16(g_, aq0, P0); MFMA16(g_, aq1, P1); \
  _Pragma("unroll") for (int r_ = 0; r_ < 4; r_++) { \
    int jj_ = q4 * 4 + r_ - 16 * (U) - cc + 63; \
    if ((unsigned)jj_ < 64u) Sb[(arow + q4 * 4 + r_) * 136 + jj_ * 2] = (__bf16)(g_[r_] * 0.8660254f); } }
#define HT(U, NT, P0, P1, K0, K1) { f32x4 h_ = {}; MFMA16(h_, P0, K0); MFMA16(h_, P1, K1); \
  _Pragma("unroll") for (int r_ = 0; r_ < 4; r_++) { \
    int ar_ = 16 * (U) + q4 * 4 + r_ + 16 * (NT) + cc - 63; \
    if ((unsigned)ar_ < 16u) Sb[(arow + ar_) * 136 + (16 * (NT) + cc) * 2 + 1] = (__bf16)h_[r_]; } }
#define CT(NT, K0, K1) { f32x4 c_ = {}; MFMA16(c_, aq0, K0); MFMA16(c_, aq1, K1); accc[NT] = c_; }

  // loop-carried prefetch state: K tile (4 pairs) + pos U=4 pair for CURRENT jt
  v8bf k00,k01,k10,k11,k20,k21,k30,k31;
  v8bf pn0, pn1;
  LDKJ(k00,k01,0,0); LDKJ(k10,k11,1,0); LDKJ(k20,k21,2,0); LDKJ(k30,k31,3,0);
  LDPN(pn0, pn1, i0 + arow + 449 + 64);   // jt=0: pw0 + 64

  for (int jt = 0; jt < 8; jt++) {
    const int j0 = jt * 64;
    const int pw0 = i0 + arow - j0 + 449;
    const int jn = (j0 + 64 <= 448) ? (j0 + 64) : 448;   // next-tile base (clamped)

    float mk[4];
    #pragma unroll
    for (int nt = 0; nt < 4; nt++) mk[nt] = mask[(size_t)b * S + j0 + nt * 16 + cc];

    f32x4 accc[4];
    v8bf p30,p31,p20,p21,p10,p11,p00,p01;

    LDPN(p30, p31, pw0 + 48);
    GT(4, pn0, pn1); HT(4, 0, pn0, pn1, k00, k01); CT(0, k00, k01);
    LDPN(p20, p21, pw0 + 32);
    GT(3, p30, p31); HT(3, 0, p30, p31, k00, k01); HT(3, 1, p30, p31, k10, k11); CT(1, k10, k11);
    LDKJ(k00, k01, 0, jn);          // k00/k01 dead -> reload for next tile
    LDPN(p10, p11, pw0 + 16);
    GT(2, p20, p21); HT(2, 1, p20, p21, k10, k11); HT(2, 2, p20, p21, k20, k21); CT(2, k20, k21);
    LDKJ(k10, k11, 1, jn);
    LDPN(p00, p01, pw0);
    GT(1, p10, p11); HT(1, 2, p10, p11, k20, k21); HT(1, 3, p10, p11, k30, k31); CT(3, k30, k31);
    LDKJ(k20, k21, 2, jn);
    GT(0, p00, p01); HT(0, 3, p00, p01, k30, k31);
    LDKJ(k30, k31, 3, jn);
    LDPN(pn0, pn1, pw0);            // next jt's U=4 pair: next_pw0 + 64 == pw0

    float sc[4][4];
    #pragma unroll
    for (int nt = 0; nt < 4; nt++) {
      int jj = nt * 16 + cc;
      #pragma unroll
      for (int r = 0; r < 4; r++) {
        const __bf16* slot = &Sb[(arow + q4 * 4 + r) * 136 + jj * 2];
        sc[nt][r] = accc[nt][r] + (float)slot[0] + (float)slot[1] + mk[nt];
      }
    }

    // T13 defer-max: per-lane local max; full reduce + rescale only if needed
    float tl[4];
    #pragma unroll
    for (int r = 0; r < 4; r++)
      tl[r] = fmaxf(fmaxf(sc[0][r], sc[1][r]), fmaxf(sc[2][r], sc[3][r]));
    float dmax = tl[0] - mrow[0];
    #pragma unroll
    for (int r = 1; r < 4; r++) dmax = fmaxf(dmax, tl[r] - mrow[r]);

    if (__any(dmax > 8.0f)) {
      float tmax[4];
      #pragma unroll
      for (int r = 0; r < 4; r++) tmax[r] = tl[r];
      #pragma unroll
      for (int off = 1; off < 16; off <<= 1)
        #pragma unroll
        for (int r = 0; r < 4; r++) tmax[r] = fmaxf(tmax[r], __shfl_xor(tmax[r], off, 64));
      #pragma unroll
      for (int r = 0; r < 4; r++) {
        float mnew = fmaxf(mrow[r], tmax[r]);
        float alpha = __expf(mrow[r] - mnew);
        mrow[r] = mnew;
        lrow[r] *= alpha;
        #pragma unroll
        for (int dt = 0; dt < 4; dt++) Oc[dt][r] *= alpha;
      }
    }

    v8bf vf[2][4];
    #pragma unroll
    for (int kk = 0; kk < 2; kk++)
      #pragma unroll
      for (int dt = 0; dt < 4; dt++)
        vf[kk][dt] = *(const v8bf*)(&vtp[(size_t)(dt * 16 + cc) * S + j0 + kk * 32 + q4 * 8]);

    float psum[4] = { 0.f, 0.f, 0.f, 0.f };
    #pragma unroll
    for (int nt = 0; nt < 4; nt++)
      #pragma unroll
      for (int r = 0; r < 4; r++) {
        float p = __expf(sc[nt][r] - mrow[r]);
        psum[r] += p;
        Sb[(arow + q4 * 4 + r) * 136 + nt * 16 + cc] = (__bf16)p;
      }
    #pragma unroll
    for (int off = 1; off < 16; off <<= 1)
      #pragma unroll
      for (int r = 0; r < 4; r++) psum[r] += __shfl_xor(psum[r], off, 64);
    #pragma unroll
    for (int r = 0; r < 4; r++) lrow[r] += psum[r];

    #pragma unroll
    for (int kk = 0; kk < 2; kk++) {
      v8bf ap = *(const v8bf*)(&Sb[(arow + cc) * 136 + kk * 32 + q4 * 8]);
      #pragma unroll
      for (int dt = 0; dt < 4; dt++)
        MFMA16(Oc[dt], ap, vf[kk][dt]);
    }
  }

  // epilogue: normalize and store fp32 output directly
  #pragma unroll
  for (int r = 0; r < 4; r++) {
    int i = i0 + arow + q4 * 4 + r;
    float rl = 1.0f / lrow[r];
    float* orow = &out[((size_t)b * S + i) * HID + h * 64];
    #pragma unroll
    for (int dt = 0; dt < 4; dt++)
      orow[dt * 16 + cc] = Oc[dt][r] * rl;
  }
#undef LDPN
#undef LDKJ
#undef GT
#undef HT
#undef CT
}

// ---------------- launch ----------------
extern "C" void kernel_launch(void* const* d_in, const int* in_sizes, int n_in,
                              void* d_out, int out_size, void* d_ws, size_t ws_size,
                              hipStream_t stream) {
  const float* hs   = (const float*)d_in[0];
  const float* mask = (const float*)d_in[1];
  const float* Wq  = (const float*)d_in[3];
  const float* bq  = (const float*)d_in[4];
  const float* Wk  = (const float*)d_in[5];
  const float* bk  = (const float*)d_in[6];
  const float* Wv  = (const float*)d_in[7];
  const float* bv  = (const float*)d_in[8];
  const float* Wpk = (const float*)d_in[9];
  const float* bpk = (const float*)d_in[10];
  const float* rel = (const float*)d_in[11];
  float* out = (float*)d_out;

  char* ws = (char*)d_ws;
  __bf16* cb   = (__bf16*)ws;                      // casts: X|Wq|Wk|Wv|Wpk|rel = 18 MB
  __bf16* Xb   = cb;
  __bf16* Wqb  = cb + 4194304;
  __bf16* Wkb  = cb + 5242880;
  __bf16* Wvb  = cb + 6291456;
  __bf16* Wpkb = cb + 7340032;
  __bf16* Rb   = cb + 8388608;
  __bf16* qb   = (__bf16*)(ws + 18874368);         // [b][h][s][d] 8 MB (pre-scaled)
  __bf16* kb   = (__bf16*)(ws + 27262976);         // [b][h][s][d] 8 MB
  __bf16* vtb  = (__bf16*)(ws + 35651584);         // [b][h][d][s] 8 MB
  __bf16* posb = (__bf16*)(ws + 44040192);         // [h][p][d]    2 MB (pre-scaled)

  castall<<<9216, 256, 0, stream>>>(hs, Wq, Wk, Wv, Wpk, rel, cb);

  proj_gemm<<<dim3(32, 8, 4), 256, 0, stream>>>(Xb, Rb, Wqb, Wkb, Wvb, Wpkb,
                                                bq, bk, bv, bpk, qb, kb, vtb, posb);

  attn<<<dim3(8, 128), 256, 0, stream>>>(qb, kb, vtb, posb, mask, out);
}